// Round 4
// baseline (68.544 us; speedup 1.0000x reference)
//
#include <hip/hip_runtime.h>
#include <stdint.h>

#define BATCH 8
#define NNODE 1024
#define INF 768
#define OUTF 512
#define MTOT (BATCH * NNODE) /* 8192 */

typedef __attribute__((ext_vector_type(8))) short short8;
typedef __attribute__((ext_vector_type(4))) short short4v;
typedef __attribute__((ext_vector_type(4))) float floatx4;

__device__ __forceinline__ unsigned short f2bf(float f) {
  union { float f; unsigned u; } v; v.f = f;
  unsigned r = v.u + 0x7fffu + ((v.u >> 16) & 1u);
  return (unsigned short)(r >> 16);
}

__device__ __forceinline__ void gload_lds16(const void* g, void* l) {
  __builtin_amdgcn_global_load_lds(
      (const __attribute__((address_space(1))) void*)g,
      (__attribute__((address_space(3))) void*)l, 16, 0, 0);
}

// ------------- prep: h->bf16 (+zero f12), W -> Wt (512x768 bf16) -------------
__global__ __launch_bounds__(256) void prep_kernel(
    const float* __restrict__ h, const float* __restrict__ W,
    short* __restrict__ hbf, short* __restrict__ Wt, float* __restrict__ f12) {
  __shared__ float tile[32][33];
  int bid = blockIdx.x;
  int t = threadIdx.x;
  if (bid < 3072) {
    size_t i = ((size_t)bid * 256 + t) * 8;
    float4 v0 = *(const float4*)&h[i];
    float4 v1 = *(const float4*)&h[i + 4];
    short8 o;
    o[0] = (short)f2bf(v0.x); o[1] = (short)f2bf(v0.y);
    o[2] = (short)f2bf(v0.z); o[3] = (short)f2bf(v0.w);
    o[4] = (short)f2bf(v1.x); o[5] = (short)f2bf(v1.y);
    o[6] = (short)f2bf(v1.z); o[7] = (short)f2bf(v1.w);
    *(short8*)&hbf[i] = o;
    if (bid < 16) {
      float4 z = make_float4(0.f, 0.f, 0.f, 0.f);
      *(float4*)&f12[bid * 1024 + t * 4] = z;
    }
  } else {
    int tb = bid - 3072;             // 384 tiles: 16 (o) x 24 (k)
    int o0 = (tb & 15) * 32;
    int k0 = (tb >> 4) * 32;
    int x = t & 31, y = t >> 5;
#pragma unroll
    for (int q = 0; q < 4; ++q) {
      int r = y * 4 + q;
      tile[r][x] = W[(size_t)(k0 + r) * OUTF + o0 + x];
    }
    __syncthreads();
#pragma unroll
    for (int q = 0; q < 4; ++q) {
      int r = y * 4 + q;
      Wt[(size_t)(o0 + r) * INF + k0 + x] = (short)f2bf(tile[x][r]);
    }
  }
}

// ---- GEMM1 fused: Wh = h@W + pos  ->  Wht (bf16, transposed) + f1/f2 ----
__global__ __launch_bounds__(512) void gemm1_kernel(
    const short* __restrict__ hbf, const short* __restrict__ Wt,
    const int* __restrict__ positions, const float* __restrict__ pos_table,
    const float* __restrict__ a, float* __restrict__ f12,
    short* __restrict__ Wht) {
  __shared__ short smem[4][8192];   // A0,B0,A1,B1 (16KB each)
  int bid0 = blockIdx.x;
  int bid = (bid0 & 7) * 32 + (bid0 >> 3);   // XCD swizzle (256 % 8 == 0)
  int nt = bid & 3, mt = bid >> 2;
  int M0 = mt * 128, N0 = nt * 128;
  int t = threadIdx.x;
  int wv = t >> 6, lane = t & 63;
  int wr = (wv >> 2) * 64, wc = (wv & 3) * 32;
  int l16 = lane & 15, kq = lane >> 4;

  floatx4 acc[4][2] = {};

  auto stage = [&](int buf, int kt) {
#pragma unroll
    for (int i = 0; i < 2; ++i) {
      int q = wv * 64 + lane + i * 512;
      int row = q >> 3;
      int cg = (q & 7) ^ (row & 7);   // inverse-swizzled global source
      gload_lds16(&hbf[(size_t)(M0 + row) * INF + kt * 64 + cg * 8],
                  &smem[buf * 2][(wv * 64 + i * 512) * 8]);
      gload_lds16(&Wt[(size_t)(N0 + row) * INF + kt * 64 + cg * 8],
                  &smem[buf * 2 + 1][(wv * 64 + i * 512) * 8]);
    }
  };

  stage(0, 0);
  __syncthreads();
  int cur = 0;
  for (int kt = 0; kt < 12; ++kt) {
    if (kt < 11) stage(cur ^ 1, kt + 1);
    const short* As = smem[cur * 2];
    const short* Bs = smem[cur * 2 + 1];
#pragma unroll
    for (int ks = 0; ks < 2; ++ks) {
      short8 af[4], bfv[2];
#pragma unroll
      for (int mi = 0; mi < 4; ++mi) {
        int r = wr + mi * 16 + l16;
        af[mi] = *(const short8*)&As[r * 64 + (((ks * 4 + kq) ^ (r & 7)) * 8)];
      }
#pragma unroll
      for (int ni = 0; ni < 2; ++ni) {
        int r = wc + ni * 16 + l16;
        bfv[ni] = *(const short8*)&Bs[r * 64 + (((ks * 4 + kq) ^ (r & 7)) * 8)];
      }
#pragma unroll
      for (int mi = 0; mi < 4; ++mi)
#pragma unroll
        for (int ni = 0; ni < 2; ++ni)
          acc[mi][ni] = __builtin_amdgcn_mfma_f32_16x16x32_bf16(af[mi], bfv[ni], acc[mi][ni], 0, 0, 0);
    }
    __syncthreads();
    cur ^= 1;
  }

  // ---- epilogue ----
  int oc0 = N0 + wc + l16;
  int oc1 = oc0 + 16;
#pragma unroll
  for (int mi = 0; mi < 4; ++mi)
#pragma unroll
    for (int j = 0; j < 4; ++j) {
      int row = M0 + wr + mi * 16 + kq * 4 + j;
      int pos = positions[row];
      acc[mi][0][j] += pos_table[(size_t)pos * OUTF + oc0];
      acc[mi][1][j] += pos_table[(size_t)pos * OUTF + oc1];
    }
  short* T = &smem[0][0];   // 128*136 shorts transposed tile
#pragma unroll
  for (int mi = 0; mi < 4; ++mi)
#pragma unroll
    for (int ni = 0; ni < 2; ++ni)
#pragma unroll
      for (int j = 0; j < 4; ++j)
        T[(wc + ni * 16 + l16) * 136 + wr + mi * 16 + kq * 4 + j] =
            (short)f2bf(acc[mi][ni][j]);
  float a10 = a[oc0], a11 = a[oc1];
  float a20 = a[OUTF + oc0], a21 = a[OUTF + oc1];
  float v1[16], v2[16];
#pragma unroll
  for (int mi = 0; mi < 4; ++mi)
#pragma unroll
    for (int j = 0; j < 4; ++j) {
      v1[mi * 4 + j] = acc[mi][0][j] * a10 + acc[mi][1][j] * a11;
      v2[mi * 4 + j] = acc[mi][0][j] * a20 + acc[mi][1][j] * a21;
    }
#pragma unroll
  for (int mlen = 8; mlen >= 1; mlen >>= 1) {
    bool hi = (l16 & mlen) != 0;
#pragma unroll
    for (int i = 0; i < mlen; ++i) {
      float k1 = hi ? v1[mlen + i] : v1[i];
      float s1 = hi ? v1[i] : v1[mlen + i];
      float k2 = hi ? v2[mlen + i] : v2[i];
      float s2 = hi ? v2[i] : v2[mlen + i];
      v1[i] = k1 + __shfl_xor(s1, mlen);
      v2[i] = k2 + __shfl_xor(s2, mlen);
    }
  }
  {
    int rrow = M0 + wr + (l16 >> 2) * 16 + kq * 4 + (l16 & 3);
    atomicAdd(&f12[rrow], v1[0]);
    atomicAdd(&f12[MTOT + rrow], v2[0]);
  }
  __syncthreads();
  int bb = M0 >> 10, i0 = M0 & 1023;
#pragma unroll
  for (int i = 0; i < 4; ++i) {
    int c = t + i * 512;
    int row = c >> 4;
    int mc = (c & 15) * 8;
    short8 vv = *(const short8*)&T[row * 136 + mc];
    *(short8*)&Wht[((size_t)bb * OUTF + N0 + row) * NNODE + i0 + mc] = vv;
  }
}

// ---- fused softmax + PV: one block = 32 rows of one batch ----
// Phase A: masked leaky-relu softmax, att f32 out, p bf16 -> LDS (swizzled).
// Phase B: h' rows = p @ Wht[batch], K=1024, kstep=32, B double-buffered.
__global__ __launch_bounds__(512) void smpv_kernel(
    const float* __restrict__ f12, const int* __restrict__ adj,
    const short* __restrict__ Wht, float* __restrict__ att,
    float* __restrict__ hp) {
  __shared__ short lds[65536];       // 128KB: pbf 32768 | B0 16384 | B1 16384
  short* pbf = lds;
  short* Bbuf0 = lds + 32768;
  short* Bbuf1 = lds + 49152;

  int bid0 = blockIdx.x;
  int b = bid0 & 7, rb = bid0 >> 3;  // batch -> XCD (matches gemm1 swizzle)
  int r0 = rb * 32;
  int t = threadIdx.x;
  int wv = t >> 6, lane = t & 63;
  int l16 = lane & 15, kq = lane >> 4;
  const short* Wb = Wht + (size_t)b * OUTF * NNODE;

  auto stageB = [&](short* dst, int kt) {
#pragma unroll
    for (int i = 0; i < 4; ++i) {
      int q = wv * 64 + lane + i * 512;   // 0..2047 chunk id
      int r = q >> 2, s = q & 3;
      int cg = s ^ (r & 3);               // inverse-swizzled source chunk
      gload_lds16(&Wb[(size_t)r * NNODE + kt * 32 + cg * 8],
                  dst + (wv * 64 + i * 512) * 8);
    }
  };
  stageB(Bbuf0, 0);   // hide first B tile under softmax

  // ---- phase A ----
  {
    int row = t >> 4, sub = t & 15;
    int gm = b * NNODE + r0 + row;
    float f1v = f12[gm];
    const float* f2b = f12 + MTOT + b * NNODE;
    const int* adjrow = adj + (size_t)gm * NNODE;
    float e[64];
#pragma unroll
    for (int i = 0; i < 16; ++i) {
      int col = sub * 4 + i * 64;
      int4 av = *(const int4*)&adjrow[col];
      float4 fv = *(const float4*)&f2b[col];
      float x;
      x = f1v + fv.x; x = x >= 0.f ? x : 0.2f * x; e[i * 4 + 0] = av.x > 0 ? x : -9e15f;
      x = f1v + fv.y; x = x >= 0.f ? x : 0.2f * x; e[i * 4 + 1] = av.y > 0 ? x : -9e15f;
      x = f1v + fv.z; x = x >= 0.f ? x : 0.2f * x; e[i * 4 + 2] = av.z > 0 ? x : -9e15f;
      x = f1v + fv.w; x = x >= 0.f ? x : 0.2f * x; e[i * 4 + 3] = av.w > 0 ? x : -9e15f;
    }
    float mx = e[0];
#pragma unroll
    for (int i = 1; i < 64; ++i) mx = fmaxf(mx, e[i]);
#pragma unroll
    for (int off = 1; off < 16; off <<= 1) mx = fmaxf(mx, __shfl_xor(mx, off));
    float s = 0.f;
#pragma unroll
    for (int i = 0; i < 64; ++i) { e[i] = expf(e[i] - mx); s += e[i]; }
#pragma unroll
    for (int off = 1; off < 16; off <<= 1) s += __shfl_xor(s, off);
    float inv = 1.f / s;
    float* attrow = att + (size_t)gm * NNODE;
#pragma unroll
    for (int i = 0; i < 16; ++i) {
      int col = sub * 4 + i * 64;
      float4 o = make_float4(e[i * 4] * inv, e[i * 4 + 1] * inv,
                             e[i * 4 + 2] * inv, e[i * 4 + 3] * inv);
      *(float4*)&attrow[col] = o;
      int c = (sub >> 1) + 8 * i;        // 16B-chunk index 0..127
      short4v pb;
      pb[0] = (short)f2bf(o.x); pb[1] = (short)f2bf(o.y);
      pb[2] = (short)f2bf(o.z); pb[3] = (short)f2bf(o.w);
      *(short4v*)&pbf[row * 1024 + ((c ^ (row & 7)) * 8) + (sub & 1) * 4] = pb;
    }
  }
  __syncthreads();   // pbf ready; Bbuf0 staged (vmcnt drained at barrier)

  // ---- phase B: PV ----
  int wc = wv * 64;
  floatx4 acc[2][4] = {};
  int cur = 0;
  for (int kt = 0; kt < 32; ++kt) {
    if (kt < 31) stageB(cur ? Bbuf0 : Bbuf1, kt + 1);
    const short* Bsc = cur ? Bbuf1 : Bbuf0;
    short8 af[2], bfv[4];
#pragma unroll
    for (int mi = 0; mi < 2; ++mi) {
      int r = mi * 16 + l16;
      af[mi] = *(const short8*)&pbf[r * 1024 + (((kt * 4 + kq) ^ (r & 7)) * 8)];
    }
#pragma unroll
    for (int ni = 0; ni < 4; ++ni) {
      int r = wc + ni * 16 + l16;
      bfv[ni] = *(const short8*)&Bsc[r * 32 + ((kq ^ (r & 3)) * 8)];
    }
#pragma unroll
    for (int mi = 0; mi < 2; ++mi)
#pragma unroll
      for (int ni = 0; ni < 4; ++ni)
        acc[mi][ni] = __builtin_amdgcn_mfma_f32_16x16x32_bf16(af[mi], bfv[ni], acc[mi][ni], 0, 0, 0);
    __syncthreads();
    cur ^= 1;
  }

#pragma unroll
  for (int mi = 0; mi < 2; ++mi)
#pragma unroll
    for (int j = 0; j < 4; ++j) {
      int grow = b * NNODE + r0 + mi * 16 + kq * 4 + j;
#pragma unroll
      for (int ni = 0; ni < 4; ++ni)
        hp[(size_t)grow * OUTF + wc + ni * 16 + l16] = acc[mi][ni][j];
    }
}

extern "C" void kernel_launch(void* const* d_in, const int* in_sizes, int n_in,
                              void* d_out, int out_size, void* d_ws, size_t ws_size,
                              hipStream_t stream) {
  const float* h = (const float*)d_in[0];
  const int* adj = (const int*)d_in[1];
  const int* positions = (const int*)d_in[2];
  const float* W = (const float*)d_in[3];
  const float* a = (const float*)d_in[4];
  const float* pos_table = (const float*)d_in[5];

  float* hp = (float*)d_out;                       // 8192*512
  float* att = hp + (size_t)MTOT * OUTF;           // 8192*1024

  char* ws = (char*)d_ws;
  short* Wt = (short*)ws;                                   // 786432 B
  short* Wht = (short*)(ws + 786432);                       // 8388608 B
  float* f12 = (float*)(ws + 786432 + 8388608);             // 65536 B
  short* hbf = (short*)(ws + 786432 + 8388608 + 65536);     // 12582912 B

  prep_kernel<<<3456, 256, 0, stream>>>(h, W, hbf, Wt, f12);
  gemm1_kernel<<<256, 512, 0, stream>>>(hbf, Wt, positions, pos_table, a, f12, Wht);
  smpv_kernel<<<256, 512, 0, stream>>>(f12, adj, Wht, att, hp);
}

// Round 5
// 59.746 us; speedup vs baseline: 1.1473x; 1.1473x over previous
//
#include <hip/hip_runtime.h>
#include <stdint.h>

#define BATCH 8
#define NNODE 1024
#define INF 768
#define OUTF 512
#define MTOT (BATCH * NNODE) /* 8192 */

typedef __attribute__((ext_vector_type(8))) short short8;
typedef __attribute__((ext_vector_type(4))) short short4v;
typedef __attribute__((ext_vector_type(4))) float floatx4;

__device__ __forceinline__ unsigned short f2bf(float f) {
  union { float f; unsigned u; } v; v.f = f;
  unsigned r = v.u + 0x7fffu + ((v.u >> 16) & 1u);
  return (unsigned short)(r >> 16);
}

__device__ __forceinline__ void gload_lds16(const void* g, void* l) {
  __builtin_amdgcn_global_load_lds(
      (const __attribute__((address_space(1))) void*)g,
      (__attribute__((address_space(3))) void*)l, 16, 0, 0);
}

// ------------- prep: h->bf16 (+zero f12), W -> Wt (512x768 bf16) -------------
__global__ __launch_bounds__(256) void prep_kernel(
    const float* __restrict__ h, const float* __restrict__ W,
    short* __restrict__ hbf, short* __restrict__ Wt, float* __restrict__ f12) {
  __shared__ float tile[32][33];
  int bid = blockIdx.x;
  int t = threadIdx.x;
  if (bid < 3072) {
    size_t i = ((size_t)bid * 256 + t) * 8;
    float4 v0 = *(const float4*)&h[i];
    float4 v1 = *(const float4*)&h[i + 4];
    short8 o;
    o[0] = (short)f2bf(v0.x); o[1] = (short)f2bf(v0.y);
    o[2] = (short)f2bf(v0.z); o[3] = (short)f2bf(v0.w);
    o[4] = (short)f2bf(v1.x); o[5] = (short)f2bf(v1.y);
    o[6] = (short)f2bf(v1.z); o[7] = (short)f2bf(v1.w);
    *(short8*)&hbf[i] = o;
    if (bid < 16) {
      float4 z = make_float4(0.f, 0.f, 0.f, 0.f);
      *(float4*)&f12[bid * 1024 + t * 4] = z;
    }
  } else {
    int tb = bid - 3072;             // 384 tiles: 16 (o) x 24 (k)
    int o0 = (tb & 15) * 32;
    int k0 = (tb >> 4) * 32;
    int x = t & 31, y = t >> 5;
#pragma unroll
    for (int q = 0; q < 4; ++q) {
      int r = y * 4 + q;
      tile[r][x] = W[(size_t)(k0 + r) * OUTF + o0 + x];
    }
    __syncthreads();
#pragma unroll
    for (int q = 0; q < 4; ++q) {
      int r = y * 4 + q;
      Wt[(size_t)(o0 + r) * INF + k0 + x] = (short)f2bf(tile[x][r]);
    }
  }
}

// ---- GEMM1 fused: Wh = h@W + pos  ->  Wht (bf16, transposed) + f1/f2 ----
// BM=BN=128, BK=64, 8 waves; counted-vmcnt double-buffer (no full drains).
__global__ __launch_bounds__(512) void gemm1_kernel(
    const short* __restrict__ hbf, const short* __restrict__ Wt,
    const int* __restrict__ positions, const float* __restrict__ pos_table,
    const float* __restrict__ a, float* __restrict__ f12,
    short* __restrict__ Wht) {
  __shared__ short smem[4][8192];   // A0,B0,A1,B1 (16KB each)
  int bid0 = blockIdx.x;
  int bid = (bid0 & 7) * 32 + (bid0 >> 3);   // XCD swizzle (256 % 8 == 0)
  int nt = bid & 3, mt = bid >> 2;
  int M0 = mt * 128, N0 = nt * 128;
  int t = threadIdx.x;
  int wv = t >> 6, lane = t & 63;
  int wr = (wv >> 2) * 64, wc = (wv & 3) * 32;
  int l16 = lane & 15, kq = lane >> 4;

  floatx4 acc[4][2] = {};

  auto stage = [&](int buf, int kt) {
#pragma unroll
    for (int i = 0; i < 2; ++i) {
      int q = wv * 64 + lane + i * 512;
      int row = q >> 3;
      int cg = (q & 7) ^ (row & 7);   // inverse-swizzled global source
      gload_lds16(&hbf[(size_t)(M0 + row) * INF + kt * 64 + cg * 8],
                  &smem[buf * 2][(wv * 64 + i * 512) * 8]);
      gload_lds16(&Wt[(size_t)(N0 + row) * INF + kt * 64 + cg * 8],
                  &smem[buf * 2 + 1][(wv * 64 + i * 512) * 8]);
    }
  };

  // prefetch depth 2: tiles 0 and 1 in flight (4 loads each per wave)
  stage(0, 0);
  stage(1, 1);
  for (int kt = 0; kt < 12; ++kt) {
    // wait for own tile-kt loads (allow tile-kt+1's 4 to stay in flight)
    if (kt + 1 < 12) asm volatile("s_waitcnt vmcnt(4)" ::: "memory");
    else             asm volatile("s_waitcnt vmcnt(0)" ::: "memory");
    __builtin_amdgcn_sched_barrier(0);
    __builtin_amdgcn_s_barrier();     // all waves' tile-kt loads landed
    asm volatile("" ::: "memory");
    const short* As = smem[(kt & 1) * 2];
    const short* Bs = smem[(kt & 1) * 2 + 1];
#pragma unroll
    for (int ks = 0; ks < 2; ++ks) {
      short8 af[4], bfv[2];
#pragma unroll
      for (int mi = 0; mi < 4; ++mi) {
        int r = wr + mi * 16 + l16;
        af[mi] = *(const short8*)&As[r * 64 + (((ks * 4 + kq) ^ (r & 7)) * 8)];
      }
#pragma unroll
      for (int ni = 0; ni < 2; ++ni) {
        int r = wc + ni * 16 + l16;
        bfv[ni] = *(const short8*)&Bs[r * 64 + (((ks * 4 + kq) ^ (r & 7)) * 8)];
      }
#pragma unroll
      for (int mi = 0; mi < 4; ++mi)
#pragma unroll
        for (int ni = 0; ni < 2; ++ni)
          acc[mi][ni] = __builtin_amdgcn_mfma_f32_16x16x32_bf16(af[mi], bfv[ni], acc[mi][ni], 0, 0, 0);
    }
    asm volatile("" ::: "memory");
    __builtin_amdgcn_s_barrier();     // all waves done reading tile kt
    asm volatile("" ::: "memory");
    if (kt + 2 < 12) stage(kt & 1, kt + 2);  // overwrite tile-kt buffer
  }

  // ---- epilogue ---- (no DMAs outstanding: vmcnt(0) waited at kt=11)
  int oc0 = N0 + wc + l16;
  int oc1 = oc0 + 16;
#pragma unroll
  for (int mi = 0; mi < 4; ++mi)
#pragma unroll
    for (int j = 0; j < 4; ++j) {
      int row = M0 + wr + mi * 16 + kq * 4 + j;
      int pos = positions[row];
      acc[mi][0][j] += pos_table[(size_t)pos * OUTF + oc0];
      acc[mi][1][j] += pos_table[(size_t)pos * OUTF + oc1];
    }
  short* T = &smem[0][0];   // 128*136 shorts transposed tile
#pragma unroll
  for (int mi = 0; mi < 4; ++mi)
#pragma unroll
    for (int ni = 0; ni < 2; ++ni)
#pragma unroll
      for (int j = 0; j < 4; ++j)
        T[(wc + ni * 16 + l16) * 136 + wr + mi * 16 + kq * 4 + j] =
            (short)f2bf(acc[mi][ni][j]);
  float a10 = a[oc0], a11 = a[oc1];
  float a20 = a[OUTF + oc0], a21 = a[OUTF + oc1];
  float v1[16], v2[16];
#pragma unroll
  for (int mi = 0; mi < 4; ++mi)
#pragma unroll
    for (int j = 0; j < 4; ++j) {
      v1[mi * 4 + j] = acc[mi][0][j] * a10 + acc[mi][1][j] * a11;
      v2[mi * 4 + j] = acc[mi][0][j] * a20 + acc[mi][1][j] * a21;
    }
#pragma unroll
  for (int mlen = 8; mlen >= 1; mlen >>= 1) {
    bool hi = (l16 & mlen) != 0;
#pragma unroll
    for (int i = 0; i < mlen; ++i) {
      float k1 = hi ? v1[mlen + i] : v1[i];
      float s1 = hi ? v1[i] : v1[mlen + i];
      float k2 = hi ? v2[mlen + i] : v2[i];
      float s2 = hi ? v2[i] : v2[mlen + i];
      v1[i] = k1 + __shfl_xor(s1, mlen);
      v2[i] = k2 + __shfl_xor(s2, mlen);
    }
  }
  {
    int rrow = M0 + wr + (l16 >> 2) * 16 + kq * 4 + (l16 & 3);
    atomicAdd(&f12[rrow], v1[0]);
    atomicAdd(&f12[MTOT + rrow], v2[0]);
  }
  __syncthreads();
  int bb = M0 >> 10, i0 = M0 & 1023;
#pragma unroll
  for (int i = 0; i < 4; ++i) {
    int c = t + i * 512;
    int row = c >> 4;
    int mc = (c & 15) * 8;
    short8 vv = *(const short8*)&T[row * 136 + mc];
    *(short8*)&Wht[((size_t)bb * OUTF + N0 + row) * NNODE + i0 + mc] = vv;
  }
}

// ---- fused softmax + PV: one block = 32 rows of one batch ----
// Phase A: masked leaky-relu softmax, att f32 out, p bf16 -> LDS (swizzled).
// Phase B: h' = p @ Wht[batch], K=1024, kstep=32, counted-vmcnt dbuf.
__global__ __launch_bounds__(512) void smpv_kernel(
    const float* __restrict__ f12, const int* __restrict__ adj,
    const short* __restrict__ Wht, float* __restrict__ att,
    float* __restrict__ hp) {
  __shared__ short lds[65536];       // 128KB: pbf 64KB | B0 32KB | B1 32KB
  short* pbf = lds;
  short* Bbuf0 = lds + 32768;
  short* Bbuf1 = lds + 49152;

  int bid0 = blockIdx.x;
  int b = bid0 & 7, rb = bid0 >> 3;  // batch -> XCD (matches gemm1 swizzle)
  int r0 = rb * 32;
  int t = threadIdx.x;
  int wv = t >> 6, lane = t & 63;
  int l16 = lane & 15, kq = lane >> 4;
  const short* Wb = Wht + (size_t)b * OUTF * NNODE;

  auto stageB = [&](short* dst, int kt) {
#pragma unroll
    for (int i = 0; i < 4; ++i) {
      int q = wv * 64 + lane + i * 512;   // 0..2047 chunk id
      int r = q >> 2, s = q & 3;
      int cg = s ^ (r & 3);               // inverse-swizzled source chunk
      gload_lds16(&Wb[(size_t)r * NNODE + kt * 32 + cg * 8],
                  dst + (wv * 64 + i * 512) * 8);
    }
  };
  stageB(Bbuf0, 0);   // tiles 0,1 land during softmax
  stageB(Bbuf1, 1);

  // ---- phase A ----
  {
    int row = t >> 4, sub = t & 15;
    int gm = b * NNODE + r0 + row;
    float f1v = f12[gm];
    const float* f2b = f12 + MTOT + b * NNODE;
    const int* adjrow = adj + (size_t)gm * NNODE;
    float e[64];
#pragma unroll
    for (int i = 0; i < 16; ++i) {
      int col = sub * 4 + i * 64;
      int4 av = *(const int4*)&adjrow[col];
      float4 fv = *(const float4*)&f2b[col];
      float x;
      x = f1v + fv.x; x = x >= 0.f ? x : 0.2f * x; e[i * 4 + 0] = av.x > 0 ? x : -9e15f;
      x = f1v + fv.y; x = x >= 0.f ? x : 0.2f * x; e[i * 4 + 1] = av.y > 0 ? x : -9e15f;
      x = f1v + fv.z; x = x >= 0.f ? x : 0.2f * x; e[i * 4 + 2] = av.z > 0 ? x : -9e15f;
      x = f1v + fv.w; x = x >= 0.f ? x : 0.2f * x; e[i * 4 + 3] = av.w > 0 ? x : -9e15f;
    }
    float mx = e[0];
#pragma unroll
    for (int i = 1; i < 64; ++i) mx = fmaxf(mx, e[i]);
#pragma unroll
    for (int off = 1; off < 16; off <<= 1) mx = fmaxf(mx, __shfl_xor(mx, off));
    float s = 0.f;
#pragma unroll
    for (int i = 0; i < 64; ++i) { e[i] = expf(e[i] - mx); s += e[i]; }
#pragma unroll
    for (int off = 1; off < 16; off <<= 1) s += __shfl_xor(s, off);
    float inv = 1.f / s;
    float* attrow = att + (size_t)gm * NNODE;
#pragma unroll
    for (int i = 0; i < 16; ++i) {
      int col = sub * 4 + i * 64;
      float4 o = make_float4(e[i * 4] * inv, e[i * 4 + 1] * inv,
                             e[i * 4 + 2] * inv, e[i * 4 + 3] * inv);
      *(float4*)&attrow[col] = o;
      int c = (sub >> 1) + 8 * i;        // 16B-chunk index 0..127
      short4v pb;
      pb[0] = (short)f2bf(o.x); pb[1] = (short)f2bf(o.y);
      pb[2] = (short)f2bf(o.z); pb[3] = (short)f2bf(o.w);
      *(short4v*)&pbf[row * 1024 + ((c ^ (row & 7)) * 8) + (sub & 1) * 4] = pb;
    }
  }
  __syncthreads();   // pbf visible; drains everything (tiles 0,1 landed long ago)

  // ---- phase B: PV, counted-vmcnt double-buffer ----
  int wc = wv * 64;
  floatx4 acc[2][4] = {};
  for (int kt = 0; kt < 32; ++kt) {
    if (kt + 1 < 32) asm volatile("s_waitcnt vmcnt(4)" ::: "memory");
    else             asm volatile("s_waitcnt vmcnt(0)" ::: "memory");
    __builtin_amdgcn_sched_barrier(0);
    __builtin_amdgcn_s_barrier();     // all waves' tile-kt loads landed
    asm volatile("" ::: "memory");
    const short* Bsc = (kt & 1) ? Bbuf1 : Bbuf0;
    short8 af[2], bfv[4];
#pragma unroll
    for (int mi = 0; mi < 2; ++mi) {
      int r = mi * 16 + l16;
      af[mi] = *(const short8*)&pbf[r * 1024 + (((kt * 4 + kq) ^ (r & 7)) * 8)];
    }
#pragma unroll
    for (int ni = 0; ni < 4; ++ni) {
      int r = wc + ni * 16 + l16;
      bfv[ni] = *(const short8*)&Bsc[r * 32 + ((kq ^ (r & 3)) * 8)];
    }
#pragma unroll
    for (int mi = 0; mi < 2; ++mi)
#pragma unroll
      for (int ni = 0; ni < 4; ++ni)
        acc[mi][ni] = __builtin_amdgcn_mfma_f32_16x16x32_bf16(af[mi], bfv[ni], acc[mi][ni], 0, 0, 0);
    asm volatile("" ::: "memory");
    __builtin_amdgcn_s_barrier();     // all waves done reading tile kt
    asm volatile("" ::: "memory");
    if (kt + 2 < 32) stageB((kt & 1) ? Bbuf1 : Bbuf0, kt + 2);
  }

#pragma unroll
  for (int mi = 0; mi < 2; ++mi)
#pragma unroll
    for (int j = 0; j < 4; ++j) {
      int grow = b * NNODE + r0 + mi * 16 + kq * 4 + j;
#pragma unroll
      for (int ni = 0; ni < 4; ++ni)
        hp[(size_t)grow * OUTF + wc + ni * 16 + l16] = acc[mi][ni][j];
    }
}

extern "C" void kernel_launch(void* const* d_in, const int* in_sizes, int n_in,
                              void* d_out, int out_size, void* d_ws, size_t ws_size,
                              hipStream_t stream) {
  const float* h = (const float*)d_in[0];
  const int* adj = (const int*)d_in[1];
  const int* positions = (const int*)d_in[2];
  const float* W = (const float*)d_in[3];
  const float* a = (const float*)d_in[4];
  const float* pos_table = (const float*)d_in[5];

  float* hp = (float*)d_out;                       // 8192*512
  float* att = hp + (size_t)MTOT * OUTF;           // 8192*1024

  char* ws = (char*)d_ws;
  short* Wt = (short*)ws;                                   // 786432 B
  short* Wht = (short*)(ws + 786432);                       // 8388608 B
  float* f12 = (float*)(ws + 786432 + 8388608);             // 65536 B
  short* hbf = (short*)(ws + 786432 + 8388608 + 65536);     // 12582912 B

  prep_kernel<<<3456, 256, 0, stream>>>(h, W, hbf, Wt, f12);
  gemm1_kernel<<<256, 512, 0, stream>>>(hbf, Wt, positions, pos_table, a, f12, Wht);
  smpv_kernel<<<256, 512, 0, stream>>>(f12, adj, Wht, att, hp);
}